// Round 4
// baseline (2371.764 us; speedup 1.0000x reference)
//
#include <hip/hip_runtime.h>

#define NN 50000
#define NE 600000
#define DD 128

__device__ __forceinline__ float bf2f(unsigned int u16) {
    union { unsigned int i; float f; } v; v.i = u16 << 16; return v.f;
}
__device__ __forceinline__ unsigned short f2bf(float f) {
    union { float f; unsigned int i; } v; v.f = f;
    unsigned int i = v.i + 0x7FFFu + ((v.i >> 16) & 1u);
    return (unsigned short)(i >> 16);
}
__device__ __forceinline__ float wred64(float v) {
    #pragma unroll
    for (int o = 32; o; o >>= 1) v += __shfl_xor(v, o, 64);
    return v;
}
__device__ __forceinline__ int tame16(unsigned int u) {
    int e = (int)((u >> 7) & 0xFF);
    return (e >= 100 && e <= 133) ? 1 : 0;
}

// flags[0]=edges int64, flags[1]=x bf16, flags[2]=W bf16, flags[3]=noise bf16
__global__ void probe_k(const int* __restrict__ ei,
                        const unsigned int* __restrict__ xw,
                        const unsigned int* __restrict__ w1w,
                        const unsigned int* __restrict__ nzw,
                        int* __restrict__ flags) {
    if (threadIdx.x == 0 && blockIdx.x == 0) {
        int allz = 1;
        for (int i = 0; i < 256; ++i)
            if (ei[2 * i + 1] != 0) { allz = 0; break; }
        flags[0] = allz;
        int tx = 0, tw = 0, tn = 0;
        for (int i = 0; i < 64; ++i) {
            tx += tame16(xw[i] & 0xFFFFu);
            tw += tame16(w1w[i] & 0xFFFFu);
            tn += tame16(nzw[i] & 0xFFFFu);
        }
        flags[1] = (tx >= 48) ? 1 : 0;
        flags[2] = (tw >= 48) ? 1 : 0;
        flags[3] = (tn >= 48) ? 1 : 0;
    }
}

// W1,b1,W2,b2 -> bf16 scratch (copy if already bf16, per flags[2])
__global__ __launch_bounds__(256) void convert_k(
    const void* __restrict__ W1, const void* __restrict__ b1,
    const void* __restrict__ W2, const void* __restrict__ b2,
    const int* __restrict__ flags,
    unsigned short* __restrict__ W1b, unsigned short* __restrict__ b1b,
    unsigned short* __restrict__ W2b, unsigned short* __restrict__ b2b) {
    const int i = blockIdx.x * blockDim.x + threadIdx.x;
    if (i >= DD * DD) return;
    if (flags[2]) {
        W1b[i] = ((const unsigned short*)W1)[i];
        W2b[i] = ((const unsigned short*)W2)[i];
        if (i < DD) { b1b[i] = ((const unsigned short*)b1)[i];
                      b2b[i] = ((const unsigned short*)b2)[i]; }
    } else {
        W1b[i] = f2bf(((const float*)W1)[i]);
        W2b[i] = f2bf(((const float*)W2)[i]);
        if (i < DD) { b1b[i] = f2bf(((const float*)b1)[i]);
                      b2b[i] = f2bf(((const float*)b2)[i]); }
    }
}

// One wave/row: featf (f32, in d_out) = clip(x); agg (f32) = clip(x) + noise1
__global__ __launch_bounds__(256) void prep_k(
    const void* __restrict__ x, const void* __restrict__ noise,
    const int* __restrict__ flags,
    float* __restrict__ featf, float* __restrict__ agg) {
    const int row = (blockIdx.x * blockDim.x + threadIdx.x) >> 6;
    const int lane = threadIdx.x & 63;
    if (row >= NN) return;
    float v0, v1, n0, n1;
    if (flags[1]) {
        const unsigned int px = ((const unsigned int*)x)[(size_t)row * 64 + lane];
        v0 = bf2f(px & 0xFFFFu); v1 = bf2f(px >> 16);
    } else {
        const float2 px = ((const float2*)x)[(size_t)row * 64 + lane];
        v0 = px.x; v1 = px.y;
    }
    if (flags[3]) {
        const unsigned int pn = ((const unsigned int*)noise)[(size_t)row * 64 + lane];
        n0 = bf2f(pn & 0xFFFFu); n1 = bf2f(pn >> 16);
    } else {
        const float2 pn = ((const float2*)noise)[(size_t)row * 64 + lane];
        n0 = pn.x; n1 = pn.y;
    }
    float ss = wred64(v0 * v0 + v1 * v1);
    const float nrm = sqrtf(ss);
    const float sc = nrm > 1.0f ? 1.0f / nrm : 1.0f;
    const float c0 = v0 * sc, c1 = v1 * sc;
    ((float2*)(featf + (size_t)row * DD))[lane] = make_float2(c0, c1);
    ((float2*)(agg + (size_t)row * DD))[lane] = make_float2(c0 + n0, c1 + n1);
}

// 32 lanes/edge: agg[dst] += feat[src]
__global__ __launch_bounds__(256) void scatter_k(
    const int* __restrict__ ei, const int* __restrict__ flags,
    const float* __restrict__ featf, float* __restrict__ agg) {
    const long long t = (long long)blockIdx.x * blockDim.x + threadIdx.x;
    const int e = (int)(t >> 5);
    const int l = (int)(t & 31);
    if (e >= NE) return;
    int s, d;
    if (flags[0]) {
        const long long* e64 = (const long long*)ei;
        s = (int)e64[e]; d = (int)e64[NE + e];
    } else {
        s = ei[e]; d = ei[NE + e];
    }
    const float4 v = ((const float4*)(featf + (size_t)s * DD))[l];
    float* dp = agg + (size_t)d * DD + l * 4;
    atomicAdd(dp + 0, v.x);
    atomicAdd(dp + 1, v.y);
    atomicAdd(dp + 2, v.z);
    atomicAdd(dp + 3, v.w);
}

// out[r][j] = sum_k A[r][k]*W[j][k] + b[j]; 8 rows/block, 256 threads.
// LAYER1: SELU -> L2 clip -> featf (f32, d_out) & agg = hc + noise2 (in place).
// LAYER2: f32 out to d_out.
template<bool LAYER1>
__global__ __launch_bounds__(256) void gemm_k(
    const float* __restrict__ A,
    const unsigned short* __restrict__ Wb,
    const unsigned short* __restrict__ bb,
    const void* __restrict__ noiseg,
    const int* __restrict__ flags,
    float* __restrict__ outf,
    float* __restrict__ agg_out) {
    __shared__ float Ar[8 * DD];
    __shared__ float red[16];
    const int t = threadIdx.x;
    const int j = t & 127;
    const int half = t >> 7;
    const int lane = t & 63;
    const int wv = t >> 6;
    const long long r0 = (long long)blockIdx.x * 8;

    #pragma unroll
    for (int i = 0; i < 4; ++i)
        Ar[t + i * 256] = A[r0 * DD + t + i * 256];

    const uint4* wp = (const uint4*)(Wb + (size_t)j * DD);
    uint4 w4[16];
    #pragma unroll
    for (int i = 0; i < 16; ++i) w4[i] = wp[i];
    const float bj = bf2f((unsigned int)bb[j]);

    __syncthreads();

    const float* A0 = &Ar[(half * 4) * DD];
    float acc0 = 0.f, acc1 = 0.f, acc2 = 0.f, acc3 = 0.f;
    const unsigned int* wr = (const unsigned int*)w4;
    #pragma unroll
    for (int kk = 0; kk < 32; ++kk) {
        const unsigned int u0 = wr[2 * kk], u1 = wr[2 * kk + 1];
        const float w0 = bf2f(u0 & 0xFFFFu);
        const float w1 = bf2f(u0 >> 16);
        const float w2 = bf2f(u1 & 0xFFFFu);
        const float w3 = bf2f(u1 >> 16);
        const int k = kk * 4;
        const float4 a0 = *(const float4*)&A0[0 * DD + k];
        const float4 a1 = *(const float4*)&A0[1 * DD + k];
        const float4 a2 = *(const float4*)&A0[2 * DD + k];
        const float4 a3 = *(const float4*)&A0[3 * DD + k];
        acc0 += a0.x * w0 + a0.y * w1 + a0.z * w2 + a0.w * w3;
        acc1 += a1.x * w0 + a1.y * w1 + a1.z * w2 + a1.w * w3;
        acc2 += a2.x * w0 + a2.y * w1 + a2.z * w2 + a2.w * w3;
        acc3 += a3.x * w0 + a3.y * w1 + a3.z * w2 + a3.w * w3;
    }

    float h0 = acc0 + bj, h1 = acc1 + bj, h2 = acc2 + bj, h3 = acc3 + bj;
    const size_t base = (size_t)(r0 + half * 4) * DD + j;

    if (LAYER1) {
        const float S = 1.0507009873554805f, AL = 1.6732632423543772f;
        h0 = h0 > 0.f ? S * h0 : S * AL * expm1f(h0);
        h1 = h1 > 0.f ? S * h1 : S * AL * expm1f(h1);
        h2 = h2 > 0.f ? S * h2 : S * AL * expm1f(h2);
        h3 = h3 > 0.f ? S * h3 : S * AL * expm1f(h3);
        const float s0 = wred64(h0 * h0);
        const float s1 = wred64(h1 * h1);
        const float s2 = wred64(h2 * h2);
        const float s3 = wred64(h3 * h3);
        if (lane == 0) {
            red[wv * 4 + 0] = s0; red[wv * 4 + 1] = s1;
            red[wv * 4 + 2] = s2; red[wv * 4 + 3] = s3;
        }
        __syncthreads();
        const int rb = half * 8;
        const float nr0 = sqrtf(red[rb + 0] + red[rb + 4]);
        const float nr1 = sqrtf(red[rb + 1] + red[rb + 5]);
        const float nr2 = sqrtf(red[rb + 2] + red[rb + 6]);
        const float nr3 = sqrtf(red[rb + 3] + red[rb + 7]);
        const float sc0 = nr0 > 1.f ? 1.f / nr0 : 1.f;
        const float sc1 = nr1 > 1.f ? 1.f / nr1 : 1.f;
        const float sc2 = nr2 > 1.f ? 1.f / nr2 : 1.f;
        const float sc3 = nr3 > 1.f ? 1.f / nr3 : 1.f;
        const float v0 = h0 * sc0, v1 = h1 * sc1, v2 = h2 * sc2, v3 = h3 * sc3;
        float n0, n1, n2, n3;
        if (flags[3]) {
            n0 = bf2f((unsigned int)((const unsigned short*)noiseg)[base + 0 * DD]);
            n1 = bf2f((unsigned int)((const unsigned short*)noiseg)[base + 1 * DD]);
            n2 = bf2f((unsigned int)((const unsigned short*)noiseg)[base + 2 * DD]);
            n3 = bf2f((unsigned int)((const unsigned short*)noiseg)[base + 3 * DD]);
        } else {
            n0 = ((const float*)noiseg)[base + 0 * DD];
            n1 = ((const float*)noiseg)[base + 1 * DD];
            n2 = ((const float*)noiseg)[base + 2 * DD];
            n3 = ((const float*)noiseg)[base + 3 * DD];
        }
        outf[base + 0 * DD] = v0;
        outf[base + 1 * DD] = v1;
        outf[base + 2 * DD] = v2;
        outf[base + 3 * DD] = v3;
        agg_out[base + 0 * DD] = v0 + n0;
        agg_out[base + 1 * DD] = v1 + n1;
        agg_out[base + 2 * DD] = v2 + n2;
        agg_out[base + 3 * DD] = v3 + n3;
    } else {
        outf[base + 0 * DD] = h0;
        outf[base + 1 * DD] = h1;
        outf[base + 2 * DD] = h2;
        outf[base + 3 * DD] = h3;
    }
}

extern "C" void kernel_launch(void* const* d_in, const int* in_sizes, int n_in,
                              void* d_out, int out_size, void* d_ws, size_t ws_size,
                              hipStream_t stream) {
    const void* x  = d_in[0];
    const int*  ei = (const int*)d_in[1];
    const void* W1 = d_in[2];
    const void* b1 = d_in[3];
    const void* W2 = d_in[4];
    const void* b2 = d_in[5];
    const void* n1 = d_in[6];
    const void* n2 = d_in[7];

    // ws (~25.7 MB): agg f32 [NN*DD], bf16 weights, flags
    float* agg = (float*)d_ws;
    unsigned short* W1b = (unsigned short*)(agg + (size_t)NN * DD);
    unsigned short* b1b = W1b + DD * DD;
    unsigned short* W2b = b1b + DD;
    unsigned short* b2b = W2b + DD * DD;
    int* flags = (int*)(b2b + DD);
    // clipped features (f32) live in d_out (25.6 MB, exact fit); final GEMM
    // overwrites them last and never reads them.
    float* featf = (float*)d_out;

    probe_k<<<1, 64, 0, stream>>>(ei, (const unsigned int*)x,
                                  (const unsigned int*)W1,
                                  (const unsigned int*)n1, flags);
    convert_k<<<(DD * DD + 255) / 256, 256, 0, stream>>>(W1, b1, W2, b2, flags,
                                                         W1b, b1b, W2b, b2b);

    // Layer 1
    prep_k<<<(NN * 64) / 256, 256, 0, stream>>>(x, n1, flags, featf, agg);
    scatter_k<<<(NE * 32) / 256, 256, 0, stream>>>(ei, flags, featf, agg);
    gemm_k<true><<<NN / 8, 256, 0, stream>>>(agg, W1b, b1b, n2, flags,
                                             featf, agg);

    // Layer 2 (featf/d_out holds hc; agg holds agg2 = hc + noise2)
    scatter_k<<<(NE * 32) / 256, 256, 0, stream>>>(ei, flags, featf, agg);
    gemm_k<false><<<NN / 8, 256, 0, stream>>>(agg, W2b, b2b, nullptr, flags,
                                              (float*)d_out, nullptr);
}

// Round 5
// 557.583 us; speedup vs baseline: 4.2537x; 4.2537x over previous
//
#include <hip/hip_runtime.h>

#define NN 50000
#define NE 600000
#define DD 128

__device__ __forceinline__ float bf2f(unsigned int u16) {
    union { unsigned int i; float f; } v; v.i = u16 << 16; return v.f;
}
__device__ __forceinline__ unsigned short f2bf(float f) {
    union { float f; unsigned int i; } v; v.f = f;
    unsigned int i = v.i + 0x7FFFu + ((v.i >> 16) & 1u);
    return (unsigned short)(i >> 16);
}
__device__ __forceinline__ float wred64(float v) {
    #pragma unroll
    for (int o = 32; o; o >>= 1) v += __shfl_xor(v, o, 64);
    return v;
}
__device__ __forceinline__ int tame16(unsigned int u) {
    int e = (int)((u >> 7) & 0xFF);
    return (e >= 100 && e <= 133) ? 1 : 0;
}

// flags[0]=edges int64, flags[1]=x bf16, flags[2]=W bf16, flags[3]=noise bf16
__global__ void probe_k(const int* __restrict__ ei,
                        const unsigned int* __restrict__ xw,
                        const unsigned int* __restrict__ w1w,
                        const unsigned int* __restrict__ nzw,
                        int* __restrict__ flags) {
    if (threadIdx.x == 0 && blockIdx.x == 0) {
        int allz = 1;
        for (int i = 0; i < 256; ++i)
            if (ei[2 * i + 1] != 0) { allz = 0; break; }
        flags[0] = allz;
        int tx = 0, tw = 0, tn = 0;
        for (int i = 0; i < 64; ++i) {
            tx += tame16(xw[i] & 0xFFFFu);
            tw += tame16(w1w[i] & 0xFFFFu);
            tn += tame16(nzw[i] & 0xFFFFu);
        }
        flags[1] = (tx >= 48) ? 1 : 0;
        flags[2] = (tw >= 48) ? 1 : 0;
        flags[3] = (tn >= 48) ? 1 : 0;
    }
}

__global__ __launch_bounds__(256) void convert_k(
    const void* __restrict__ W1, const void* __restrict__ b1,
    const void* __restrict__ W2, const void* __restrict__ b2,
    const int* __restrict__ flags,
    unsigned short* __restrict__ W1b, unsigned short* __restrict__ b1b,
    unsigned short* __restrict__ W2b, unsigned short* __restrict__ b2b) {
    const int i = blockIdx.x * blockDim.x + threadIdx.x;
    if (i >= DD * DD) return;
    if (flags[2]) {
        W1b[i] = ((const unsigned short*)W1)[i];
        W2b[i] = ((const unsigned short*)W2)[i];
        if (i < DD) { b1b[i] = ((const unsigned short*)b1)[i];
                      b2b[i] = ((const unsigned short*)b2)[i]; }
    } else {
        W1b[i] = f2bf(((const float*)W1)[i]);
        W2b[i] = f2bf(((const float*)W2)[i]);
        if (i < DD) { b1b[i] = f2bf(((const float*)b1)[i]);
                      b2b[i] = f2bf(((const float*)b2)[i]); }
    }
}

// ---- CSR build ----
__global__ __launch_bounds__(256) void hist_k(
    const int* __restrict__ ei, const int* __restrict__ flags,
    int* __restrict__ deg) {
    const int e = blockIdx.x * blockDim.x + threadIdx.x;
    if (e >= NE) return;
    const int d = flags[0] ? (int)((const long long*)ei)[NE + e] : ei[NE + e];
    atomicAdd(&deg[d], 1);
}

// exclusive scan of deg[NN] -> offs[NN+1]; cursor = copy of offs[0..NN)
__global__ __launch_bounds__(1024) void scan_k(
    const int* __restrict__ deg, int* __restrict__ offs,
    int* __restrict__ cursor) {
    __shared__ int wsum[16];
    __shared__ int wbase[16];
    __shared__ int carry_s;
    const int tid = threadIdx.x, lane = tid & 63, wv = tid >> 6;
    if (tid == 0) carry_s = 0;
    __syncthreads();
    for (int base = 0; base < NN; base += 1024) {
        const int i = base + tid;
        const int v = (i < NN) ? deg[i] : 0;
        int incl = v;
        #pragma unroll
        for (int off = 1; off < 64; off <<= 1) {
            int t = __shfl_up(incl, off, 64);
            if (lane >= off) incl += t;
        }
        if (lane == 63) wsum[wv] = incl;
        __syncthreads();
        if (wv == 0 && lane < 16) {
            const int wv_v = wsum[lane];
            int wincl = wv_v;
            #pragma unroll
            for (int off = 1; off < 16; off <<= 1) {
                int t = __shfl_up(wincl, off, 64);
                if (lane >= off) wincl += t;
            }
            wbase[lane] = wincl - wv_v;
            if (lane == 15) wsum[0] = wincl;   // chunk total (reads done above)
        }
        __syncthreads();
        const int carry = carry_s;
        if (i < NN) {
            const int excl = carry + wbase[wv] + incl - v;
            offs[i] = excl;
            cursor[i] = excl;
        }
        __syncthreads();
        if (tid == 0) carry_s = carry + wsum[0];
        __syncthreads();
    }
    if (threadIdx.x == 0) offs[NN] = carry_s;
}

__global__ __launch_bounds__(256) void fill_k(
    const int* __restrict__ ei, const int* __restrict__ flags,
    int* __restrict__ cursor, int* __restrict__ eidx) {
    const int e = blockIdx.x * blockDim.x + threadIdx.x;
    if (e >= NE) return;
    int s, d;
    if (flags[0]) {
        const long long* e64 = (const long long*)ei;
        s = (int)e64[e]; d = (int)e64[NE + e];
    } else {
        s = ei[e]; d = ei[NE + e];
    }
    const int pos = atomicAdd(&cursor[d], 1);
    eidx[pos] = s;
}

// One wave/row: featf (f32, in d_out) = clip(x)
__global__ __launch_bounds__(256) void prep_k(
    const void* __restrict__ x, const int* __restrict__ flags,
    float* __restrict__ featf) {
    const int row = (blockIdx.x * blockDim.x + threadIdx.x) >> 6;
    const int lane = threadIdx.x & 63;
    if (row >= NN) return;
    float v0, v1;
    if (flags[1]) {
        const unsigned int px = ((const unsigned int*)x)[(size_t)row * 64 + lane];
        v0 = bf2f(px & 0xFFFFu); v1 = bf2f(px >> 16);
    } else {
        const float2 px = ((const float2*)x)[(size_t)row * 64 + lane];
        v0 = px.x; v1 = px.y;
    }
    const float ss = wred64(v0 * v0 + v1 * v1);
    const float nrm = sqrtf(ss);
    const float sc = nrm > 1.0f ? 1.0f / nrm : 1.0f;
    ((float2*)(featf + (size_t)row * DD))[lane] = make_float2(v0 * sc, v1 * sc);
}

// One wave/node: agg[n] = feat[n] + noise[n] + sum_{e in CSR[n]} feat[src(e)]
__global__ __launch_bounds__(256) void agg_k(
    const int* __restrict__ offs, const int* __restrict__ eidx,
    const float* __restrict__ feat, const void* __restrict__ noise,
    const int* __restrict__ flags, float* __restrict__ agg) {
    const int node = (blockIdx.x * blockDim.x + threadIdx.x) >> 6;
    const int lane = threadIdx.x & 63;
    if (node >= NN) return;
    const float2* f2 = (const float2*)feat;
    float2 acc = f2[(size_t)node * 64 + lane];
    if (flags[3]) {
        const unsigned int pn = ((const unsigned int*)noise)[(size_t)node * 64 + lane];
        acc.x += bf2f(pn & 0xFFFFu); acc.y += bf2f(pn >> 16);
    } else {
        const float2 n = ((const float2*)noise)[(size_t)node * 64 + lane];
        acc.x += n.x; acc.y += n.y;
    }
    const int e1 = offs[node + 1];
    int e = offs[node];
    for (; e + 1 < e1; e += 2) {
        const int s0 = eidx[e], s1 = eidx[e + 1];
        const float2 a = f2[(size_t)s0 * 64 + lane];
        const float2 b = f2[(size_t)s1 * 64 + lane];
        acc.x += a.x + b.x; acc.y += a.y + b.y;
    }
    if (e < e1) {
        const int s0 = eidx[e];
        const float2 a = f2[(size_t)s0 * 64 + lane];
        acc.x += a.x; acc.y += a.y;
    }
    ((float2*)agg)[(size_t)node * 64 + lane] = acc;
}

// out[r][j] = sum_k A[r][k]*W[j][k] + b[j]; 8 rows/block, 256 threads.
// LAYER1: SELU -> L2 clip -> outf (hc, f32 in d_out). LAYER2: raw f32 out.
template<bool LAYER1>
__global__ __launch_bounds__(256) void gemm_k(
    const float* __restrict__ A,
    const unsigned short* __restrict__ Wb,
    const unsigned short* __restrict__ bb,
    float* __restrict__ outf) {
    __shared__ float Ar[8 * DD];
    __shared__ float red[16];
    const int t = threadIdx.x;
    const int j = t & 127;
    const int half = t >> 7;
    const int lane = t & 63;
    const int wv = t >> 6;
    const long long r0 = (long long)blockIdx.x * 8;

    #pragma unroll
    for (int i = 0; i < 4; ++i)
        Ar[t + i * 256] = A[r0 * DD + t + i * 256];

    const uint4* wp = (const uint4*)(Wb + (size_t)j * DD);
    uint4 w4[16];
    #pragma unroll
    for (int i = 0; i < 16; ++i) w4[i] = wp[i];
    const float bj = bf2f((unsigned int)bb[j]);

    __syncthreads();

    const float* A0 = &Ar[(half * 4) * DD];
    float acc0 = 0.f, acc1 = 0.f, acc2 = 0.f, acc3 = 0.f;
    const unsigned int* wr = (const unsigned int*)w4;
    #pragma unroll
    for (int kk = 0; kk < 32; ++kk) {
        const unsigned int u0 = wr[2 * kk], u1 = wr[2 * kk + 1];
        const float w0 = bf2f(u0 & 0xFFFFu);
        const float w1 = bf2f(u0 >> 16);
        const float w2 = bf2f(u1 & 0xFFFFu);
        const float w3 = bf2f(u1 >> 16);
        const int k = kk * 4;
        const float4 a0 = *(const float4*)&A0[0 * DD + k];
        const float4 a1 = *(const float4*)&A0[1 * DD + k];
        const float4 a2 = *(const float4*)&A0[2 * DD + k];
        const float4 a3 = *(const float4*)&A0[3 * DD + k];
        acc0 += a0.x * w0 + a0.y * w1 + a0.z * w2 + a0.w * w3;
        acc1 += a1.x * w0 + a1.y * w1 + a1.z * w2 + a1.w * w3;
        acc2 += a2.x * w0 + a2.y * w1 + a2.z * w2 + a2.w * w3;
        acc3 += a3.x * w0 + a3.y * w1 + a3.z * w2 + a3.w * w3;
    }

    float h0 = acc0 + bj, h1 = acc1 + bj, h2 = acc2 + bj, h3 = acc3 + bj;
    const size_t base = (size_t)(r0 + half * 4) * DD + j;

    if (LAYER1) {
        const float S = 1.0507009873554805f, AL = 1.6732632423543772f;
        h0 = h0 > 0.f ? S * h0 : S * AL * expm1f(h0);
        h1 = h1 > 0.f ? S * h1 : S * AL * expm1f(h1);
        h2 = h2 > 0.f ? S * h2 : S * AL * expm1f(h2);
        h3 = h3 > 0.f ? S * h3 : S * AL * expm1f(h3);
        const float s0 = wred64(h0 * h0);
        const float s1 = wred64(h1 * h1);
        const float s2 = wred64(h2 * h2);
        const float s3 = wred64(h3 * h3);
        if (lane == 0) {
            red[wv * 4 + 0] = s0; red[wv * 4 + 1] = s1;
            red[wv * 4 + 2] = s2; red[wv * 4 + 3] = s3;
        }
        __syncthreads();
        const int rb = half * 8;
        const float nr0 = sqrtf(red[rb + 0] + red[rb + 4]);
        const float nr1 = sqrtf(red[rb + 1] + red[rb + 5]);
        const float nr2 = sqrtf(red[rb + 2] + red[rb + 6]);
        const float nr3 = sqrtf(red[rb + 3] + red[rb + 7]);
        const float sc0 = nr0 > 1.f ? 1.f / nr0 : 1.f;
        const float sc1 = nr1 > 1.f ? 1.f / nr1 : 1.f;
        const float sc2 = nr2 > 1.f ? 1.f / nr2 : 1.f;
        const float sc3 = nr3 > 1.f ? 1.f / nr3 : 1.f;
        outf[base + 0 * DD] = h0 * sc0;
        outf[base + 1 * DD] = h1 * sc1;
        outf[base + 2 * DD] = h2 * sc2;
        outf[base + 3 * DD] = h3 * sc3;
    } else {
        outf[base + 0 * DD] = h0;
        outf[base + 1 * DD] = h1;
        outf[base + 2 * DD] = h2;
        outf[base + 3 * DD] = h3;
    }
}

extern "C" void kernel_launch(void* const* d_in, const int* in_sizes, int n_in,
                              void* d_out, int out_size, void* d_ws, size_t ws_size,
                              hipStream_t stream) {
    const void* x  = d_in[0];
    const int*  ei = (const int*)d_in[1];
    const void* W1 = d_in[2];
    const void* b1 = d_in[3];
    const void* W2 = d_in[4];
    const void* b2 = d_in[5];
    const void* n1 = d_in[6];
    const void* n2 = d_in[7];

    // ws layout (~28.5 MB)
    float* agg = (float*)d_ws;                                   // NN*DD f32
    unsigned short* W1b = (unsigned short*)(agg + (size_t)NN * DD);
    unsigned short* b1b = W1b + DD * DD;
    unsigned short* W2b = b1b + DD;
    unsigned short* b2b = W2b + DD * DD;
    int* flags  = (int*)(b2b + DD);                              // 4
    int* deg    = flags + 4;                                     // NN
    int* offs   = deg + NN;                                      // NN+1
    int* cursor = offs + NN + 1;                                 // NN
    int* eidx   = cursor + NN;                                   // NE
    // clipped features / hc (f32) live in d_out; final GEMM overwrites last.
    float* featf = (float*)d_out;

    probe_k<<<1, 64, 0, stream>>>(ei, (const unsigned int*)x,
                                  (const unsigned int*)W1,
                                  (const unsigned int*)n1, flags);
    convert_k<<<(DD * DD + 255) / 256, 256, 0, stream>>>(W1, b1, W2, b2, flags,
                                                         W1b, b1b, W2b, b2b);

    // CSR build (edges identical for both layers)
    hipMemsetAsync(deg, 0, NN * sizeof(int), stream);
    hist_k<<<(NE + 255) / 256, 256, 0, stream>>>(ei, flags, deg);
    scan_k<<<1, 1024, 0, stream>>>(deg, offs, cursor);
    fill_k<<<(NE + 255) / 256, 256, 0, stream>>>(ei, flags, cursor, eidx);

    // Layer 1
    prep_k<<<(NN * 64) / 256, 256, 0, stream>>>(x, flags, featf);
    agg_k<<<(NN * 64) / 256, 256, 0, stream>>>(offs, eidx, featf, n1, flags, agg);
    gemm_k<true><<<NN / 8, 256, 0, stream>>>(agg, W1b, b1b, featf);

    // Layer 2 (featf/d_out holds hc)
    agg_k<<<(NN * 64) / 256, 256, 0, stream>>>(offs, eidx, featf, n2, flags, agg);
    gemm_k<false><<<NN / 8, 256, 0, stream>>>(agg, W2b, b2b, (float*)d_out);
}

// Round 6
// 356.484 us; speedup vs baseline: 6.6532x; 1.5641x over previous
//
#include <hip/hip_runtime.h>

#define NN 50000
#define NE 600000
#define DD 128
#define NPAD 50048   // 782 * 64

typedef __attribute__((ext_vector_type(8))) short bf16x8;
typedef __attribute__((ext_vector_type(4))) float f32x4;

__device__ __forceinline__ float bf2f(unsigned int u16) {
    union { unsigned int i; float f; } v; v.i = u16 << 16; return v.f;
}
__device__ __forceinline__ unsigned short f2bf(float f) {
    union { float f; unsigned int i; } v; v.f = f;
    unsigned int i = v.i + 0x7FFFu + ((v.i >> 16) & 1u);
    return (unsigned short)(i >> 16);
}
__device__ __forceinline__ float wred64(float v) {
    #pragma unroll
    for (int o = 32; o; o >>= 1) v += __shfl_xor(v, o, 64);
    return v;
}
__device__ __forceinline__ int tame16(unsigned int u) {
    int e = (int)((u >> 7) & 0xFF);
    return (e >= 100 && e <= 133) ? 1 : 0;
}

// flags[0]=edges int64, flags[1]=x bf16, flags[2]=W bf16, flags[3]=noise bf16
__global__ void probe_k(const int* __restrict__ ei,
                        const unsigned int* __restrict__ xw,
                        const unsigned int* __restrict__ w1w,
                        const unsigned int* __restrict__ nzw,
                        int* __restrict__ flags) {
    if (threadIdx.x == 0 && blockIdx.x == 0) {
        int allz = 1;
        for (int i = 0; i < 256; ++i)
            if (ei[2 * i + 1] != 0) { allz = 0; break; }
        flags[0] = allz;
        int tx = 0, tw = 0, tn = 0;
        for (int i = 0; i < 64; ++i) {
            tx += tame16(xw[i] & 0xFFFFu);
            tw += tame16(w1w[i] & 0xFFFFu);
            tn += tame16(nzw[i] & 0xFFFFu);
        }
        flags[1] = (tx >= 48) ? 1 : 0;
        flags[2] = (tw >= 48) ? 1 : 0;
        flags[3] = (tn >= 48) ? 1 : 0;
    }
}

__global__ __launch_bounds__(256) void convert_k(
    const void* __restrict__ W1, const void* __restrict__ b1,
    const void* __restrict__ W2, const void* __restrict__ b2,
    const int* __restrict__ flags,
    unsigned short* __restrict__ W1b, unsigned short* __restrict__ b1b,
    unsigned short* __restrict__ W2b, unsigned short* __restrict__ b2b) {
    const int i = blockIdx.x * blockDim.x + threadIdx.x;
    if (i >= DD * DD) return;
    if (flags[2]) {
        W1b[i] = ((const unsigned short*)W1)[i];
        W2b[i] = ((const unsigned short*)W2)[i];
        if (i < DD) { b1b[i] = ((const unsigned short*)b1)[i];
                      b2b[i] = ((const unsigned short*)b2)[i]; }
    } else {
        W1b[i] = f2bf(((const float*)W1)[i]);
        W2b[i] = f2bf(((const float*)W2)[i]);
        if (i < DD) { b1b[i] = f2bf(((const float*)b1)[i]);
                      b2b[i] = f2bf(((const float*)b2)[i]); }
    }
}

// ---- CSR build ----
__global__ __launch_bounds__(256) void hist_k(
    const int* __restrict__ ei, const int* __restrict__ flags,
    int* __restrict__ deg) {
    const int e = blockIdx.x * blockDim.x + threadIdx.x;
    if (e >= NE) return;
    const int d = flags[0] ? (int)((const long long*)ei)[NE + e] : ei[NE + e];
    atomicAdd(&deg[d], 1);
}

__global__ __launch_bounds__(1024) void scan_k(
    const int* __restrict__ deg, int* __restrict__ offs,
    int* __restrict__ cursor) {
    __shared__ int wsum[16];
    __shared__ int wbase[16];
    __shared__ int carry_s;
    const int tid = threadIdx.x, lane = tid & 63, wv = tid >> 6;
    if (tid == 0) carry_s = 0;
    __syncthreads();
    for (int base = 0; base < NN; base += 1024) {
        const int i = base + tid;
        const int v = (i < NN) ? deg[i] : 0;
        int incl = v;
        #pragma unroll
        for (int off = 1; off < 64; off <<= 1) {
            int t = __shfl_up(incl, off, 64);
            if (lane >= off) incl += t;
        }
        if (lane == 63) wsum[wv] = incl;
        __syncthreads();
        if (wv == 0 && lane < 16) {
            const int wv_v = wsum[lane];
            int wincl = wv_v;
            #pragma unroll
            for (int off = 1; off < 16; off <<= 1) {
                int t = __shfl_up(wincl, off, 64);
                if (lane >= off) wincl += t;
            }
            wbase[lane] = wincl - wv_v;
            if (lane == 15) wsum[0] = wincl;
        }
        __syncthreads();
        const int carry = carry_s;
        if (i < NN) {
            const int excl = carry + wbase[wv] + incl - v;
            offs[i] = excl;
            cursor[i] = excl;
        }
        __syncthreads();
        if (tid == 0) carry_s = carry + wsum[0];
        __syncthreads();
    }
    if (threadIdx.x == 0) offs[NN] = carry_s;
}

__global__ __launch_bounds__(256) void fill_k(
    const int* __restrict__ ei, const int* __restrict__ flags,
    int* __restrict__ cursor, int* __restrict__ eidx) {
    const int e = blockIdx.x * blockDim.x + threadIdx.x;
    if (e >= NE) return;
    int s, d;
    if (flags[0]) {
        const long long* e64 = (const long long*)ei;
        s = (int)e64[e]; d = (int)e64[NE + e];
    } else {
        s = ei[e]; d = ei[NE + e];
    }
    const int pos = atomicAdd(&cursor[d], 1);
    eidx[pos] = s;
}

// One wave/row: featu (packed bf16, in d_out) = clip(x)
__global__ __launch_bounds__(256) void prep_k(
    const void* __restrict__ x, const int* __restrict__ flags,
    unsigned int* __restrict__ featu) {
    const int row = (blockIdx.x * blockDim.x + threadIdx.x) >> 6;
    const int lane = threadIdx.x & 63;
    if (row >= NN) return;
    float v0, v1;
    if (flags[1]) {
        const unsigned int px = ((const unsigned int*)x)[(size_t)row * 64 + lane];
        v0 = bf2f(px & 0xFFFFu); v1 = bf2f(px >> 16);
    } else {
        const float2 px = ((const float2*)x)[(size_t)row * 64 + lane];
        v0 = px.x; v1 = px.y;
    }
    const float ss = wred64(v0 * v0 + v1 * v1);
    const float nrm = sqrtf(ss);
    const float sc = nrm > 1.0f ? 1.0f / nrm : 1.0f;
    featu[(size_t)row * 64 + lane] =
        (unsigned int)f2bf(v0 * sc) | ((unsigned int)f2bf(v1 * sc) << 16);
}

// One wave/node: aggu[n] = pack_bf16( feat[n] + noise[n] + sum feat[src] )
__global__ __launch_bounds__(256) void agg_k(
    const int* __restrict__ offs, const int* __restrict__ eidx,
    const unsigned int* __restrict__ featu, const void* __restrict__ noise,
    const int* __restrict__ flags, unsigned int* __restrict__ aggu) {
    const int node = (blockIdx.x * blockDim.x + threadIdx.x) >> 6;
    const int lane = threadIdx.x & 63;
    if (node >= NN) return;
    const unsigned int u0 = featu[(size_t)node * 64 + lane];
    float ax = bf2f(u0 & 0xFFFFu), ay = bf2f(u0 >> 16);
    if (flags[3]) {
        const unsigned int pn = ((const unsigned int*)noise)[(size_t)node * 64 + lane];
        ax += bf2f(pn & 0xFFFFu); ay += bf2f(pn >> 16);
    } else {
        const float2 n = ((const float2*)noise)[(size_t)node * 64 + lane];
        ax += n.x; ay += n.y;
    }
    const int e1 = offs[node + 1];
    int e = offs[node];
    for (; e + 1 < e1; e += 2) {
        const unsigned int a = featu[(size_t)eidx[e] * 64 + lane];
        const unsigned int b = featu[(size_t)eidx[e + 1] * 64 + lane];
        ax += bf2f(a & 0xFFFFu) + bf2f(b & 0xFFFFu);
        ay += bf2f(a >> 16) + bf2f(b >> 16);
    }
    if (e < e1) {
        const unsigned int a = featu[(size_t)eidx[e] * 64 + lane];
        ax += bf2f(a & 0xFFFFu);
        ay += bf2f(a >> 16);
    }
    aggu[(size_t)node * 64 + lane] =
        (unsigned int)f2bf(ax) | ((unsigned int)f2bf(ay) << 16);
}

// MFMA GEMM: C[r][j] = sum_k agg[r][k] * W[j][k] + b[j].
// 64 rows/block (4 waves x 16 rows), full 128 cols per wave.
// LAYER1: SELU -> row L2 clip -> featb (bf16). LAYER2: f32 out.
template<bool LAYER1>
__global__ __launch_bounds__(256) void gemm_k(
    const unsigned short* __restrict__ aggb,   // NPAD x 128 bf16
    const unsigned short* __restrict__ Wb,     // 128 x 128 bf16 (row-major)
    const unsigned short* __restrict__ bb,     // 128 bf16
    unsigned short* __restrict__ featb,        // LAYER1 output
    float* __restrict__ outf) {                // LAYER2 output
    __shared__ unsigned short Wl[128 * 136];   // +8 pad: kills quad bank conflict
    __shared__ unsigned short bl[128];
    const int t = threadIdx.x;
    // stage W (vectorized, 8 bf16 chunks stay within a row since 8|128)
    #pragma unroll
    for (int i = 0; i < 8; ++i) {
        const int idx8 = t + i * 256;
        const int base = idx8 * 8;
        const int row = base >> 7, col = base & 127;
        *(uint4*)&Wl[row * 136 + col] = ((const uint4*)Wb)[idx8];
    }
    if (t < 128) bl[t] = bb[t];

    const int lane = t & 63;
    const int w = t >> 6;
    const int n15 = lane & 15;
    const int quad = lane >> 4;
    const int rbase = blockIdx.x * 64 + w * 16;

    // A fragments: A[m=lane&15][k = quad*8 + j + kc*32]
    bf16x8 af[4];
    #pragma unroll
    for (int kc = 0; kc < 4; ++kc)
        af[kc] = *(const bf16x8*)&aggb[(size_t)(rbase + n15) * DD + kc * 32 + quad * 8];

    __syncthreads();

    float h[32];
    #pragma unroll
    for (int nt = 0; nt < 8; ++nt) {
        f32x4 acc = {0.f, 0.f, 0.f, 0.f};
        #pragma unroll
        for (int kc = 0; kc < 4; ++kc) {
            // B[k][n] = W[nt*16 + n][k]; same lane layout as A
            const bf16x8 bfr =
                *(const bf16x8*)&Wl[(nt * 16 + n15) * 136 + kc * 32 + quad * 8];
            acc = __builtin_amdgcn_mfma_f32_16x16x32_bf16(af[kc], bfr, acc, 0, 0, 0);
        }
        const float bj = bf2f((unsigned int)bl[nt * 16 + n15]);
        #pragma unroll
        for (int r = 0; r < 4; ++r) h[nt * 4 + r] = acc[r] + bj;
    }

    if (LAYER1) {
        const float S = 1.0507009873554805f, AL = 1.6732632423543772f;
        float ss[4] = {0.f, 0.f, 0.f, 0.f};
        #pragma unroll
        for (int nt = 0; nt < 8; ++nt)
            #pragma unroll
            for (int r = 0; r < 4; ++r) {
                float v = h[nt * 4 + r];
                v = v > 0.f ? S * v : S * AL * expm1f(v);
                h[nt * 4 + r] = v;
                ss[r] += v * v;
            }
        // row m = quad*4 + r lives entirely in this 16-lane quad
        #pragma unroll
        for (int r = 0; r < 4; ++r) {
            #pragma unroll
            for (int off = 1; off < 16; off <<= 1)
                ss[r] += __shfl_xor(ss[r], off, 64);
        }
        float sc[4];
        #pragma unroll
        for (int r = 0; r < 4; ++r) {
            const float nr = sqrtf(ss[r]);
            sc[r] = nr > 1.f ? 1.f / nr : 1.f;
        }
        #pragma unroll
        for (int r = 0; r < 4; ++r) {
            const int row = rbase + quad * 4 + r;
            if (row < NN) {
                #pragma unroll
                for (int nt = 0; nt < 8; ++nt)
                    featb[(size_t)row * DD + nt * 16 + n15] =
                        f2bf(h[nt * 4 + r] * sc[r]);
            }
        }
    } else {
        #pragma unroll
        for (int r = 0; r < 4; ++r) {
            const int row = rbase + quad * 4 + r;
            if (row < NN) {
                #pragma unroll
                for (int nt = 0; nt < 8; ++nt)
                    outf[(size_t)row * DD + nt * 16 + n15] = h[nt * 4 + r];
            }
        }
    }
}

extern "C" void kernel_launch(void* const* d_in, const int* in_sizes, int n_in,
                              void* d_out, int out_size, void* d_ws, size_t ws_size,
                              hipStream_t stream) {
    const void* x  = d_in[0];
    const int*  ei = (const int*)d_in[1];
    const void* W1 = d_in[2];
    const void* b1 = d_in[3];
    const void* W2 = d_in[4];
    const void* b2 = d_in[5];
    const void* n1 = d_in[6];
    const void* n2 = d_in[7];

    // ws layout (~15.9 MB)
    unsigned short* aggb = (unsigned short*)d_ws;        // NPAD*128 bf16
    unsigned short* W1b  = aggb + (size_t)NPAD * DD;
    unsigned short* b1b  = W1b + DD * DD;
    unsigned short* W2b  = b1b + DD;
    unsigned short* b2b  = W2b + DD * DD;
    int* flags  = (int*)(b2b + DD);
    int* deg    = flags + 4;
    int* offs   = deg + NN;
    int* cursor = offs + NN + 1;
    int* eidx   = cursor + NN;
    // clipped features / hc (packed bf16) live in d_out's first half
    unsigned int* featu = (unsigned int*)d_out;

    probe_k<<<1, 64, 0, stream>>>(ei, (const unsigned int*)x,
                                  (const unsigned int*)W1,
                                  (const unsigned int*)n1, flags);
    convert_k<<<(DD * DD + 255) / 256, 256, 0, stream>>>(W1, b1, W2, b2, flags,
                                                         W1b, b1b, W2b, b2b);

    // CSR build (edges identical for both layers)
    hipMemsetAsync(deg, 0, NN * sizeof(int), stream);
    hist_k<<<(NE + 255) / 256, 256, 0, stream>>>(ei, flags, deg);
    scan_k<<<1, 1024, 0, stream>>>(deg, offs, cursor);
    fill_k<<<(NE + 255) / 256, 256, 0, stream>>>(ei, flags, cursor, eidx);

    // Layer 1
    prep_k<<<(NN * 64) / 256, 256, 0, stream>>>(x, flags, featu);
    agg_k<<<(NN * 64) / 256, 256, 0, stream>>>(offs, eidx, featu, n1, flags,
                                               (unsigned int*)aggb);
    gemm_k<true><<<NPAD / 64, 256, 0, stream>>>(aggb, W1b, b1b,
                                                (unsigned short*)featu, nullptr);

    // Layer 2 (featu/d_out holds hc bf16)
    agg_k<<<(NN * 64) / 256, 256, 0, stream>>>(offs, eidx, featu, n2, flags,
                                               (unsigned int*)aggb);
    gemm_k<false><<<NPAD / 64, 256, 0, stream>>>(aggb, W2b, b2b, nullptr,
                                                 (float*)d_out);
}

// Round 9
// 290.990 us; speedup vs baseline: 8.1507x; 1.2251x over previous
//
#include <hip/hip_runtime.h>

#define NN 50000
#define NE 600000
#define DD 128
#define NPAD 50048   // 782 * 64
#define SCAN_BLOCKS 49  // ceil(50000/1024)

typedef __attribute__((ext_vector_type(8))) short bf16x8;
typedef __attribute__((ext_vector_type(4))) float f32x4;

__device__ __forceinline__ float bf2f(unsigned int u16) {
    union { unsigned int i; float f; } v; v.i = u16 << 16; return v.f;
}
__device__ __forceinline__ unsigned short f2bf(float f) {
    union { float f; unsigned int i; } v; v.f = f;
    unsigned int i = v.i + 0x7FFFu + ((v.i >> 16) & 1u);
    return (unsigned short)(i >> 16);
}
__device__ __forceinline__ float wred64(float v) {
    #pragma unroll
    for (int o = 32; o; o >>= 1) v += __shfl_xor(v, o, 64);
    return v;
}
__device__ __forceinline__ int tame16(unsigned int u) {
    int e = (int)((u >> 7) & 0xFF);
    return (e >= 100 && e <= 133) ? 1 : 0;
}

// flags[0]=edges int64, flags[1]=x bf16, flags[2]=W bf16, flags[3]=noise bf16
__global__ void probe_k(const int* __restrict__ ei,
                        const unsigned int* __restrict__ xw,
                        const unsigned int* __restrict__ w1w,
                        const unsigned int* __restrict__ nzw,
                        int* __restrict__ flags) {
    if (threadIdx.x == 0 && blockIdx.x == 0) {
        int allz = 1;
        for (int i = 0; i < 256; ++i)
            if (ei[2 * i + 1] != 0) { allz = 0; break; }
        flags[0] = allz;
        int tx = 0, tw = 0, tn = 0;
        for (int i = 0; i < 64; ++i) {
            tx += tame16(xw[i] & 0xFFFFu);
            tw += tame16(w1w[i] & 0xFFFFu);
            tn += tame16(nzw[i] & 0xFFFFu);
        }
        flags[1] = (tx >= 48) ? 1 : 0;
        flags[2] = (tw >= 48) ? 1 : 0;
        flags[3] = (tn >= 48) ? 1 : 0;
    }
}

__global__ __launch_bounds__(256) void convert_k(
    const void* __restrict__ W1, const void* __restrict__ b1,
    const void* __restrict__ W2, const void* __restrict__ b2,
    const int* __restrict__ flags,
    unsigned short* __restrict__ W1b, unsigned short* __restrict__ b1b,
    unsigned short* __restrict__ W2b, unsigned short* __restrict__ b2b) {
    const int i = blockIdx.x * blockDim.x + threadIdx.x;
    if (i >= DD * DD) return;
    if (flags[2]) {
        W1b[i] = ((const unsigned short*)W1)[i];
        W2b[i] = ((const unsigned short*)W2)[i];
        if (i < DD) { b1b[i] = ((const unsigned short*)b1)[i];
                      b2b[i] = ((const unsigned short*)b2)[i]; }
    } else {
        W1b[i] = f2bf(((const float*)W1)[i]);
        W2b[i] = f2bf(((const float*)W2)[i]);
        if (i < DD) { b1b[i] = f2bf(((const float*)b1)[i]);
                      b2b[i] = f2bf(((const float*)b2)[i]); }
    }
}

// ---- CSR build ----
__global__ __launch_bounds__(256) void hist_k(
    const int* __restrict__ ei, const int* __restrict__ flags,
    int* __restrict__ deg) {
    const int e = blockIdx.x * blockDim.x + threadIdx.x;
    if (e >= NE) return;
    const int d = flags[0] ? (int)((const long long*)ei)[NE + e] : ei[NE + e];
    atomicAdd(&deg[d], 1);
}

// Per-block exclusive scan of deg -> offs (block-local), block totals -> bsum
__global__ __launch_bounds__(1024) void scan1_k(
    const int* __restrict__ deg, int* __restrict__ offs,
    int* __restrict__ bsum) {
    __shared__ int wsum[16];
    __shared__ int wbase[16];
    __shared__ int tot_s;
    const int tid = threadIdx.x, lane = tid & 63, wv = tid >> 6;
    const int i = blockIdx.x * 1024 + tid;
    const int v = (i < NN) ? deg[i] : 0;
    int incl = v;
    #pragma unroll
    for (int off = 1; off < 64; off <<= 1) {
        int t = __shfl_up(incl, off, 64);
        if (lane >= off) incl += t;
    }
    if (lane == 63) wsum[wv] = incl;
    __syncthreads();
    if (wv == 0 && lane < 16) {
        const int wv_v = wsum[lane];
        int wincl = wv_v;
        #pragma unroll
        for (int off = 1; off < 16; off <<= 1) {
            int t = __shfl_up(wincl, off, 64);
            if (lane >= off) wincl += t;
        }
        wbase[lane] = wincl - wv_v;
        if (lane == 15) tot_s = wincl;
    }
    __syncthreads();
    if (i < NN) offs[i] = wbase[wv] + incl - v;
    if (tid == 0) bsum[blockIdx.x] = tot_s;
}

// Add exclusive block base; offs[NN] = NE (constant)
__global__ __launch_bounds__(1024) void scan2_k(
    int* __restrict__ offs, int* __restrict__ cursor,
    const int* __restrict__ bsum) {
    __shared__ int base_s;
    const int tid = threadIdx.x;
    if (tid < 64) {
        const int v = (tid < SCAN_BLOCKS) ? bsum[tid] : 0;
        int incl = v;
        #pragma unroll
        for (int off = 1; off < 64; off <<= 1) {
            int t = __shfl_up(incl, off, 64);
            if (tid >= off) incl += t;
        }
        if (tid == blockIdx.x) base_s = incl - v;
    }
    __syncthreads();
    const int i = blockIdx.x * 1024 + tid;
    if (i < NN) {
        const int o = offs[i] + base_s;
        offs[i] = o;
        cursor[i] = o;
    }
    if (blockIdx.x == 0 && tid == 0) offs[NN] = NE;
}

__global__ __launch_bounds__(256) void fill_k(
    const int* __restrict__ ei, const int* __restrict__ flags,
    int* __restrict__ cursor, int* __restrict__ eidx) {
    const int e = blockIdx.x * blockDim.x + threadIdx.x;
    if (e >= NE) return;
    int s, d;
    if (flags[0]) {
        const long long* e64 = (const long long*)ei;
        s = (int)e64[e]; d = (int)e64[NE + e];
    } else {
        s = ei[e]; d = ei[NE + e];
    }
    const int pos = atomicAdd(&cursor[d], 1);
    eidx[pos] = s;
}

// One wave/row: featu (packed bf16, in d_out) = clip(x)
__global__ __launch_bounds__(256) void prep_k(
    const void* __restrict__ x, const int* __restrict__ flags,
    unsigned int* __restrict__ featu) {
    const int row = (blockIdx.x * blockDim.x + threadIdx.x) >> 6;
    const int lane = threadIdx.x & 63;
    if (row >= NN) return;
    float v0, v1;
    if (flags[1]) {
        const unsigned int px = ((const unsigned int*)x)[(size_t)row * 64 + lane];
        v0 = bf2f(px & 0xFFFFu); v1 = bf2f(px >> 16);
    } else {
        const float2 px = ((const float2*)x)[(size_t)row * 64 + lane];
        v0 = px.x; v1 = px.y;
    }
    const float ss = wred64(v0 * v0 + v1 * v1);
    const float nrm = sqrtf(ss);
    const float sc = nrm > 1.0f ? 1.0f / nrm : 1.0f;
    featu[(size_t)row * 64 + lane] =
        (unsigned int)f2bf(v0 * sc) | ((unsigned int)f2bf(v1 * sc) << 16);
}

// One wave/node: aggu[n] = pack_bf16( feat[n] + noise[n] + sum feat[src] )
__global__ __launch_bounds__(256) void agg_k(
    const int* __restrict__ offs, const int* __restrict__ eidx,
    const unsigned int* __restrict__ featu, const void* __restrict__ noise,
    const int* __restrict__ flags, unsigned int* __restrict__ aggu) {
    const int node = (blockIdx.x * blockDim.x + threadIdx.x) >> 6;
    const int lane = threadIdx.x & 63;
    if (node >= NN) return;
    const unsigned int u0 = featu[(size_t)node * 64 + lane];
    float ax = bf2f(u0 & 0xFFFFu), ay = bf2f(u0 >> 16);
    if (flags[3]) {
        const unsigned int pn = ((const unsigned int*)noise)[(size_t)node * 64 + lane];
        ax += bf2f(pn & 0xFFFFu); ay += bf2f(pn >> 16);
    } else {
        const float2 n = ((const float2*)noise)[(size_t)node * 64 + lane];
        ax += n.x; ay += n.y;
    }
    const int e1 = offs[node + 1];
    int e = offs[node];
    for (; e + 3 < e1; e += 4) {
        const int s0 = eidx[e], s1 = eidx[e + 1];
        const int s2 = eidx[e + 2], s3 = eidx[e + 3];
        const unsigned int a = featu[(size_t)s0 * 64 + lane];
        const unsigned int b = featu[(size_t)s1 * 64 + lane];
        const unsigned int c = featu[(size_t)s2 * 64 + lane];
        const unsigned int d = featu[(size_t)s3 * 64 + lane];
        ax += (bf2f(a & 0xFFFFu) + bf2f(b & 0xFFFFu)) +
              (bf2f(c & 0xFFFFu) + bf2f(d & 0xFFFFu));
        ay += (bf2f(a >> 16) + bf2f(b >> 16)) +
              (bf2f(c >> 16) + bf2f(d >> 16));
    }
    for (; e < e1; ++e) {
        const unsigned int a = featu[(size_t)eidx[e] * 64 + lane];
        ax += bf2f(a & 0xFFFFu);
        ay += bf2f(a >> 16);
    }
    aggu[(size_t)node * 64 + lane] =
        (unsigned int)f2bf(ax) | ((unsigned int)f2bf(ay) << 16);
}

// MFMA GEMM: C[r][j] = sum_k agg[r][k] * W[j][k] + b[j].
// 64 rows/block (4 waves x 16 rows), full 128 cols per wave.
// LAYER1: SELU -> row L2 clip -> featb (bf16). LAYER2: f32 out.
template<bool LAYER1>
__global__ __launch_bounds__(256) void gemm_k(
    const unsigned short* __restrict__ aggb,   // NPAD x 128 bf16
    const unsigned short* __restrict__ Wb,     // 128 x 128 bf16 (row-major)
    const unsigned short* __restrict__ bb,     // 128 bf16
    unsigned short* __restrict__ featb,        // LAYER1 output
    float* __restrict__ outf) {                // LAYER2 output
    __shared__ unsigned short Wl[128 * 136];   // +8 pad: kills quad bank conflict
    __shared__ unsigned short bl[128];
    const int t = threadIdx.x;
    #pragma unroll
    for (int i = 0; i < 8; ++i) {
        const int idx8 = t + i * 256;
        const int base = idx8 * 8;
        const int row = base >> 7, col = base & 127;
        *(uint4*)&Wl[row * 136 + col] = ((const uint4*)Wb)[idx8];
    }
    if (t < 128) bl[t] = bb[t];

    const int lane = t & 63;
    const int w = t >> 6;
    const int n15 = lane & 15;
    const int quad = lane >> 4;
    const int rbase = blockIdx.x * 64 + w * 16;

    bf16x8 af[4];
    #pragma unroll
    for (int kc = 0; kc < 4; ++kc)
        af[kc] = *(const bf16x8*)&aggb[(size_t)(rbase + n15) * DD + kc * 32 + quad * 8];

    __syncthreads();

    float h[32];
    #pragma unroll
    for (int nt = 0; nt < 8; ++nt) {
        f32x4 acc = {0.f, 0.f, 0.f, 0.f};
        #pragma unroll
        for (int kc = 0; kc < 4; ++kc) {
            const bf16x8 bfr =
                *(const bf16x8*)&Wl[(nt * 16 + n15) * 136 + kc * 32 + quad * 8];
            acc = __builtin_amdgcn_mfma_f32_16x16x32_bf16(af[kc], bfr, acc, 0, 0, 0);
        }
        const float bj = bf2f((unsigned int)bl[nt * 16 + n15]);
        #pragma unroll
        for (int r = 0; r < 4; ++r) h[nt * 4 + r] = acc[r] + bj;
    }

    if (LAYER1) {
        const float S = 1.0507009873554805f, AL = 1.6732632423543772f;
        float ss[4] = {0.f, 0.f, 0.f, 0.f};
        #pragma unroll
        for (int nt = 0; nt < 8; ++nt)
            #pragma unroll
            for (int r = 0; r < 4; ++r) {
                float v = h[nt * 4 + r];
                v = v > 0.f ? S * v : S * AL * expm1f(v);
                h[nt * 4 + r] = v;
                ss[r] += v * v;
            }
        #pragma unroll
        for (int r = 0; r < 4; ++r) {
            #pragma unroll
            for (int off = 1; off < 16; off <<= 1)
                ss[r] += __shfl_xor(ss[r], off, 64);
        }
        float sc[4];
        #pragma unroll
        for (int r = 0; r < 4; ++r) {
            const float nr = sqrtf(ss[r]);
            sc[r] = nr > 1.f ? 1.f / nr : 1.f;
        }
        #pragma unroll
        for (int r = 0; r < 4; ++r) {
            const int row = rbase + quad * 4 + r;
            if (row < NN) {
                #pragma unroll
                for (int nt = 0; nt < 8; ++nt)
                    featb[(size_t)row * DD + nt * 16 + n15] =
                        f2bf(h[nt * 4 + r] * sc[r]);
            }
        }
    } else {
        #pragma unroll
        for (int r = 0; r < 4; ++r) {
            const int row = rbase + quad * 4 + r;
            if (row < NN) {
                #pragma unroll
                for (int nt = 0; nt < 8; ++nt)
                    outf[(size_t)row * DD + nt * 16 + n15] = h[nt * 4 + r];
            }
        }
    }
}

extern "C" void kernel_launch(void* const* d_in, const int* in_sizes, int n_in,
                              void* d_out, int out_size, void* d_ws, size_t ws_size,
                              hipStream_t stream) {
    const void* x  = d_in[0];
    const int*  ei = (const int*)d_in[1];
    const void* W1 = d_in[2];
    const void* b1 = d_in[3];
    const void* W2 = d_in[4];
    const void* b2 = d_in[5];
    const void* n1 = d_in[6];
    const void* n2 = d_in[7];

    // ws layout (~15.9 MB)
    unsigned short* aggb = (unsigned short*)d_ws;        // NPAD*128 bf16
    unsigned short* W1b  = aggb + (size_t)NPAD * DD;
    unsigned short* b1b  = W1b + DD * DD;
    unsigned short* W2b  = b1b + DD;
    unsigned short* b2b  = W2b + DD * DD;
    int* flags  = (int*)(b2b + DD);
    int* deg    = flags + 4;
    int* offs   = deg + NN;
    int* cursor = offs + NN + 1;
    int* bsum   = cursor + NN;
    int* eidx   = bsum + 64;
    unsigned int* featu = (unsigned int*)d_out;

    probe_k<<<1, 64, 0, stream>>>(ei, (const unsigned int*)x,
                                  (const unsigned int*)W1,
                                  (const unsigned int*)n1, flags);
    convert_k<<<(DD * DD + 255) / 256, 256, 0, stream>>>(W1, b1, W2, b2, flags,
                                                         W1b, b1b, W2b, b2b);

    // CSR build (edges identical for both layers)
    hipMemsetAsync(deg, 0, NN * sizeof(int), stream);
    hist_k<<<(NE + 255) / 256, 256, 0, stream>>>(ei, flags, deg);
    scan1_k<<<SCAN_BLOCKS, 1024, 0, stream>>>(deg, offs, bsum);
    scan2_k<<<SCAN_BLOCKS, 1024, 0, stream>>>(offs, cursor, bsum);
    fill_k<<<(NE + 255) / 256, 256, 0, stream>>>(ei, flags, cursor, eidx);

    // Layer 1
    prep_k<<<(NN * 64) / 256, 256, 0, stream>>>(x, flags, featu);
    agg_k<<<(NN * 64) / 256, 256, 0, stream>>>(offs, eidx, featu, n1, flags,
                                               (unsigned int*)aggb);
    gemm_k<true><<<NPAD / 64, 256, 0, stream>>>(aggb, W1b, b1b,
                                                (unsigned short*)featu, nullptr);

    // Layer 2 (featu/d_out holds hc bf16)
    agg_k<<<(NN * 64) / 256, 256, 0, stream>>>(offs, eidx, featu, n2, flags,
                                               (unsigned int*)aggb);
    gemm_k<false><<<NPAD / 64, 256, 0, stream>>>(aggb, W2b, b2b, nullptr,
                                                 (float*)d_out);
}

// Round 10
// 290.383 us; speedup vs baseline: 8.1677x; 1.0021x over previous
//
#include <hip/hip_runtime.h>

#define NN 50000
#define NE 600000
#define DD 128
#define NPAD 50048   // 782 * 64
#define SCAN_BLOCKS 49  // ceil(50000/1024)

typedef __attribute__((ext_vector_type(8))) short bf16x8;
typedef __attribute__((ext_vector_type(4))) float f32x4;

__device__ __forceinline__ float bf2f(unsigned int u16) {
    union { unsigned int i; float f; } v; v.i = u16 << 16; return v.f;
}
__device__ __forceinline__ unsigned short f2bf(float f) {
    union { float f; unsigned int i; } v; v.f = f;
    unsigned int i = v.i + 0x7FFFu + ((v.i >> 16) & 1u);
    return (unsigned short)(i >> 16);
}
__device__ __forceinline__ float wred64(float v) {
    #pragma unroll
    for (int o = 32; o; o >>= 1) v += __shfl_xor(v, o, 64);
    return v;
}
__device__ __forceinline__ int tame16(unsigned int u) {
    int e = (int)((u >> 7) & 0xFF);
    return (e >= 100 && e <= 133) ? 1 : 0;
}

// flags[0]=edges int64, flags[1]=x bf16, flags[2]=W bf16, flags[3]=noise bf16
// Parallel: 64 lanes, ~7 independent loads each, butterfly reduce.
__global__ void probe_k(const int* __restrict__ ei,
                        const unsigned int* __restrict__ xw,
                        const unsigned int* __restrict__ w1w,
                        const unsigned int* __restrict__ nzw,
                        int* __restrict__ flags) {
    const int lane = threadIdx.x;  // 64 threads, 1 block
    int nz = 0;
    #pragma unroll
    for (int i = 0; i < 4; ++i) nz |= ei[2 * (lane * 4 + i) + 1];
    int tx = tame16(xw[lane] & 0xFFFFu);
    int tw = tame16(w1w[lane] & 0xFFFFu);
    int tn = tame16(nzw[lane] & 0xFFFFu);
    #pragma unroll
    for (int o = 32; o; o >>= 1) {
        nz |= __shfl_xor(nz, o, 64);
        tx += __shfl_xor(tx, o, 64);
        tw += __shfl_xor(tw, o, 64);
        tn += __shfl_xor(tn, o, 64);
    }
    if (lane == 0) {
        flags[0] = (nz == 0) ? 1 : 0;
        flags[1] = (tx >= 48) ? 1 : 0;
        flags[2] = (tw >= 48) ? 1 : 0;
        flags[3] = (tn >= 48) ? 1 : 0;
    }
}

__global__ __launch_bounds__(256) void convert_k(
    const void* __restrict__ W1, const void* __restrict__ b1,
    const void* __restrict__ W2, const void* __restrict__ b2,
    const int* __restrict__ flags,
    unsigned short* __restrict__ W1b, unsigned short* __restrict__ b1b,
    unsigned short* __restrict__ W2b, unsigned short* __restrict__ b2b) {
    const int i = blockIdx.x * blockDim.x + threadIdx.x;
    if (i >= DD * DD) return;
    if (flags[2]) {
        W1b[i] = ((const unsigned short*)W1)[i];
        W2b[i] = ((const unsigned short*)W2)[i];
        if (i < DD) { b1b[i] = ((const unsigned short*)b1)[i];
                      b2b[i] = ((const unsigned short*)b2)[i]; }
    } else {
        W1b[i] = f2bf(((const float*)W1)[i]);
        W2b[i] = f2bf(((const float*)W2)[i]);
        if (i < DD) { b1b[i] = f2bf(((const float*)b1)[i]);
                      b2b[i] = f2bf(((const float*)b2)[i]); }
    }
}

// ---- CSR build ----
__global__ __launch_bounds__(256) void hist_k(
    const int* __restrict__ ei, const int* __restrict__ flags,
    int* __restrict__ deg) {
    const int e = blockIdx.x * blockDim.x + threadIdx.x;
    if (e >= NE) return;
    const int d = flags[0] ? (int)((const long long*)ei)[NE + e] : ei[NE + e];
    atomicAdd(&deg[d], 1);
}

// Per-block exclusive scan of deg -> offs (block-local), block totals -> bsum
__global__ __launch_bounds__(1024) void scan1_k(
    const int* __restrict__ deg, int* __restrict__ offs,
    int* __restrict__ bsum) {
    __shared__ int wsum[16];
    __shared__ int wbase[16];
    __shared__ int tot_s;
    const int tid = threadIdx.x, lane = tid & 63, wv = tid >> 6;
    const int i = blockIdx.x * 1024 + tid;
    const int v = (i < NN) ? deg[i] : 0;
    int incl = v;
    #pragma unroll
    for (int off = 1; off < 64; off <<= 1) {
        int t = __shfl_up(incl, off, 64);
        if (lane >= off) incl += t;
    }
    if (lane == 63) wsum[wv] = incl;
    __syncthreads();
    if (wv == 0 && lane < 16) {
        const int wv_v = wsum[lane];
        int wincl = wv_v;
        #pragma unroll
        for (int off = 1; off < 16; off <<= 1) {
            int t = __shfl_up(wincl, off, 64);
            if (lane >= off) wincl += t;
        }
        wbase[lane] = wincl - wv_v;
        if (lane == 15) tot_s = wincl;
    }
    __syncthreads();
    if (i < NN) offs[i] = wbase[wv] + incl - v;
    if (tid == 0) bsum[blockIdx.x] = tot_s;
}

// Add exclusive block base; offs[NN] = NE (constant)
__global__ __launch_bounds__(1024) void scan2_k(
    int* __restrict__ offs, int* __restrict__ cursor,
    const int* __restrict__ bsum) {
    __shared__ int base_s;
    const int tid = threadIdx.x;
    if (tid < 64) {
        const int v = (tid < SCAN_BLOCKS) ? bsum[tid] : 0;
        int incl = v;
        #pragma unroll
        for (int off = 1; off < 64; off <<= 1) {
            int t = __shfl_up(incl, off, 64);
            if (tid >= off) incl += t;
        }
        if (tid == blockIdx.x) base_s = incl - v;
    }
    __syncthreads();
    const int i = blockIdx.x * 1024 + tid;
    if (i < NN) {
        const int o = offs[i] + base_s;
        offs[i] = o;
        cursor[i] = o;
    }
    if (blockIdx.x == 0 && tid == 0) offs[NN] = NE;
}

__global__ __launch_bounds__(256) void fill_k(
    const int* __restrict__ ei, const int* __restrict__ flags,
    int* __restrict__ cursor, int* __restrict__ eidx) {
    const int e = blockIdx.x * blockDim.x + threadIdx.x;
    if (e >= NE) return;
    int s, d;
    if (flags[0]) {
        const long long* e64 = (const long long*)ei;
        s = (int)e64[e]; d = (int)e64[NE + e];
    } else {
        s = ei[e]; d = ei[NE + e];
    }
    const int pos = atomicAdd(&cursor[d], 1);
    eidx[pos] = s;
}

// One wave/row: featu (packed bf16, in d_out) = clip(x)
__global__ __launch_bounds__(256) void prep_k(
    const void* __restrict__ x, const int* __restrict__ flags,
    unsigned int* __restrict__ featu) {
    const int row = (blockIdx.x * blockDim.x + threadIdx.x) >> 6;
    const int lane = threadIdx.x & 63;
    if (row >= NN) return;
    float v0, v1;
    if (flags[1]) {
        const unsigned int px = ((const unsigned int*)x)[(size_t)row * 64 + lane];
        v0 = bf2f(px & 0xFFFFu); v1 = bf2f(px >> 16);
    } else {
        const float2 px = ((const float2*)x)[(size_t)row * 64 + lane];
        v0 = px.x; v1 = px.y;
    }
    const float ss = wred64(v0 * v0 + v1 * v1);
    const float nrm = sqrtf(ss);
    const float sc = nrm > 1.0f ? 1.0f / nrm : 1.0f;
    featu[(size_t)row * 64 + lane] =
        (unsigned int)f2bf(v0 * sc) | ((unsigned int)f2bf(v1 * sc) << 16);
}

// One wave/node: aggu[n] = pack_bf16( feat[n] + noise[n] + sum feat[src] )
__global__ __launch_bounds__(256) void agg_k(
    const int* __restrict__ offs, const int* __restrict__ eidx,
    const unsigned int* __restrict__ featu, const void* __restrict__ noise,
    const int* __restrict__ flags, unsigned int* __restrict__ aggu) {
    const int node = (blockIdx.x * blockDim.x + threadIdx.x) >> 6;
    const int lane = threadIdx.x & 63;
    if (node >= NN) return;
    const unsigned int u0 = featu[(size_t)node * 64 + lane];
    float ax = bf2f(u0 & 0xFFFFu), ay = bf2f(u0 >> 16);
    if (flags[3]) {
        const unsigned int pn = ((const unsigned int*)noise)[(size_t)node * 64 + lane];
        ax += bf2f(pn & 0xFFFFu); ay += bf2f(pn >> 16);
    } else {
        const float2 n = ((const float2*)noise)[(size_t)node * 64 + lane];
        ax += n.x; ay += n.y;
    }
    const int e1 = offs[node + 1];
    int e = offs[node];
    for (; e + 7 < e1; e += 8) {
        int sidx[8];
        #pragma unroll
        for (int q = 0; q < 8; ++q) sidx[q] = eidx[e + q];
        unsigned int u[8];
        #pragma unroll
        for (int q = 0; q < 8; ++q) u[q] = featu[(size_t)sidx[q] * 64 + lane];
        #pragma unroll
        for (int q = 0; q < 8; ++q) {
            ax += bf2f(u[q] & 0xFFFFu);
            ay += bf2f(u[q] >> 16);
        }
    }
    for (; e < e1; ++e) {
        const unsigned int a = featu[(size_t)eidx[e] * 64 + lane];
        ax += bf2f(a & 0xFFFFu);
        ay += bf2f(a >> 16);
    }
    aggu[(size_t)node * 64 + lane] =
        (unsigned int)f2bf(ax) | ((unsigned int)f2bf(ay) << 16);
}

// MFMA GEMM: C[r][j] = sum_k agg[r][k] * W[j][k] + b[j].
// 64 rows/block (4 waves x 16 rows), full 128 cols per wave.
// LAYER1: SELU -> row L2 clip -> featb (bf16). LAYER2: f32 out.
template<bool LAYER1>
__global__ __launch_bounds__(256) void gemm_k(
    const unsigned short* __restrict__ aggb,   // NPAD x 128 bf16
    const unsigned short* __restrict__ Wb,     // 128 x 128 bf16 (row-major)
    const unsigned short* __restrict__ bb,     // 128 bf16
    unsigned short* __restrict__ featb,        // LAYER1 output
    float* __restrict__ outf) {                // LAYER2 output
    __shared__ unsigned short Wl[128 * 136];   // +8 pad: kills quad bank conflict
    __shared__ unsigned short bl[128];
    const int t = threadIdx.x;
    #pragma unroll
    for (int i = 0; i < 8; ++i) {
        const int idx8 = t + i * 256;
        const int base = idx8 * 8;
        const int row = base >> 7, col = base & 127;
        *(uint4*)&Wl[row * 136 + col] = ((const uint4*)Wb)[idx8];
    }
    if (t < 128) bl[t] = bb[t];

    const int lane = t & 63;
    const int w = t >> 6;
    const int n15 = lane & 15;
    const int quad = lane >> 4;
    const int rbase = blockIdx.x * 64 + w * 16;

    bf16x8 af[4];
    #pragma unroll
    for (int kc = 0; kc < 4; ++kc)
        af[kc] = *(const bf16x8*)&aggb[(size_t)(rbase + n15) * DD + kc * 32 + quad * 8];

    __syncthreads();

    float h[32];
    #pragma unroll
    for (int nt = 0; nt < 8; ++nt) {
        f32x4 acc = {0.f, 0.f, 0.f, 0.f};
        #pragma unroll
        for (int kc = 0; kc < 4; ++kc) {
            const bf16x8 bfr =
                *(const bf16x8*)&Wl[(nt * 16 + n15) * 136 + kc * 32 + quad * 8];
            acc = __builtin_amdgcn_mfma_f32_16x16x32_bf16(af[kc], bfr, acc, 0, 0, 0);
        }
        const float bj = bf2f((unsigned int)bl[nt * 16 + n15]);
        #pragma unroll
        for (int r = 0; r < 4; ++r) h[nt * 4 + r] = acc[r] + bj;
    }

    if (LAYER1) {
        const float S = 1.0507009873554805f, AL = 1.6732632423543772f;
        float ss[4] = {0.f, 0.f, 0.f, 0.f};
        #pragma unroll
        for (int nt = 0; nt < 8; ++nt)
            #pragma unroll
            for (int r = 0; r < 4; ++r) {
                float v = h[nt * 4 + r];
                v = v > 0.f ? S * v : S * AL * expm1f(v);
                h[nt * 4 + r] = v;
                ss[r] += v * v;
            }
        #pragma unroll
        for (int r = 0; r < 4; ++r) {
            #pragma unroll
            for (int off = 1; off < 16; off <<= 1)
                ss[r] += __shfl_xor(ss[r], off, 64);
        }
        float sc[4];
        #pragma unroll
        for (int r = 0; r < 4; ++r) {
            const float nr = sqrtf(ss[r]);
            sc[r] = nr > 1.f ? 1.f / nr : 1.f;
        }
        #pragma unroll
        for (int r = 0; r < 4; ++r) {
            const int row = rbase + quad * 4 + r;
            if (row < NN) {
                #pragma unroll
                for (int nt = 0; nt < 8; ++nt)
                    featb[(size_t)row * DD + nt * 16 + n15] =
                        f2bf(h[nt * 4 + r] * sc[r]);
            }
        }
    } else {
        #pragma unroll
        for (int r = 0; r < 4; ++r) {
            const int row = rbase + quad * 4 + r;
            if (row < NN) {
                #pragma unroll
                for (int nt = 0; nt < 8; ++nt)
                    outf[(size_t)row * DD + nt * 16 + n15] = h[nt * 4 + r];
            }
        }
    }
}

extern "C" void kernel_launch(void* const* d_in, const int* in_sizes, int n_in,
                              void* d_out, int out_size, void* d_ws, size_t ws_size,
                              hipStream_t stream) {
    const void* x  = d_in[0];
    const int*  ei = (const int*)d_in[1];
    const void* W1 = d_in[2];
    const void* b1 = d_in[3];
    const void* W2 = d_in[4];
    const void* b2 = d_in[5];
    const void* n1 = d_in[6];
    const void* n2 = d_in[7];

    // ws layout (~15.9 MB)
    unsigned short* aggb = (unsigned short*)d_ws;        // NPAD*128 bf16
    unsigned short* W1b  = aggb + (size_t)NPAD * DD;
    unsigned short* b1b  = W1b + DD * DD;
    unsigned short* W2b  = b1b + DD;
    unsigned short* b2b  = W2b + DD * DD;
    int* flags  = (int*)(b2b + DD);
    int* deg    = flags + 4;
    int* offs   = deg + NN;
    int* cursor = offs + NN + 1;
    int* bsum   = cursor + NN;
    int* eidx   = bsum + 64;
    unsigned int* featu = (unsigned int*)d_out;

    probe_k<<<1, 64, 0, stream>>>(ei, (const unsigned int*)x,
                                  (const unsigned int*)W1,
                                  (const unsigned int*)n1, flags);
    convert_k<<<(DD * DD + 255) / 256, 256, 0, stream>>>(W1, b1, W2, b2, flags,
                                                         W1b, b1b, W2b, b2b);

    // CSR build (edges identical for both layers)
    hipMemsetAsync(deg, 0, NN * sizeof(int), stream);
    hist_k<<<(NE + 255) / 256, 256, 0, stream>>>(ei, flags, deg);
    scan1_k<<<SCAN_BLOCKS, 1024, 0, stream>>>(deg, offs, bsum);
    scan2_k<<<SCAN_BLOCKS, 1024, 0, stream>>>(offs, cursor, bsum);
    fill_k<<<(NE + 255) / 256, 256, 0, stream>>>(ei, flags, cursor, eidx);

    // Layer 1
    prep_k<<<(NN * 64) / 256, 256, 0, stream>>>(x, flags, featu);
    agg_k<<<(NN * 64) / 256, 256, 0, stream>>>(offs, eidx, featu, n1, flags,
                                               (unsigned int*)aggb);
    gemm_k<true><<<NPAD / 64, 256, 0, stream>>>(aggb, W1b, b1b,
                                                (unsigned short*)featu, nullptr);

    // Layer 2 (featu/d_out holds hc bf16)
    agg_k<<<(NN * 64) / 256, 256, 0, stream>>>(offs, eidx, featu, n2, flags,
                                               (unsigned int*)aggb);
    gemm_k<false><<<NPAD / 64, 256, 0, stream>>>(aggb, W2b, b2b, nullptr,
                                                 (float*)d_out);
}